// Round 17
// baseline (897.981 us; speedup 1.0000x reference)
//
#include <hip/hip_runtime.h>
#include <hip/hip_bf16.h>
#include <stdint.h>

#define NTOK 8192
#define CDIM 1024
#define DIN  2048
#define NEXP 8
#define NSLOT (NTOK * 2)

typedef __bf16 bf16x8 __attribute__((ext_vector_type(8)));
typedef float  f32x4  __attribute__((ext_vector_type(4)));

typedef __attribute__((address_space(1))) const unsigned char GBUF;
typedef __attribute__((address_space(3))) unsigned char LBUF;

__device__ __forceinline__ void gload_lds16(const void* g, void* l) {
    __builtin_amdgcn_global_load_lds((GBUF*)g, (LBUF*)l, 16, 0, 0);
}

__device__ __forceinline__ unsigned f2bf1(float f) {
    union { float f; unsigned u; } v; v.f = f;
    unsigned u = v.u;
    u += 0x7fffu + ((u >> 16) & 1u);   // RNE
    return u >> 16;
}
__device__ __forceinline__ ushort f2bf(float f) { return (ushort)f2bf1(f); }
__device__ __forceinline__ float bf2f(ushort u) {
    union { float f; unsigned u; } v; v.u = ((unsigned)u) << 16; return v.f;
}
__device__ __forceinline__ float silu_f(float x) { return x / (1.f + __expf(-x)); }

// pack two float4 into 8 bf16 (16 B)
__device__ __forceinline__ uint4 pack8(float4 a, float4 b) {
    uint4 o;
    o.x = f2bf1(a.x) | (f2bf1(a.y) << 16);
    o.y = f2bf1(a.z) | (f2bf1(a.w) << 16);
    o.z = f2bf1(b.x) | (f2bf1(b.y) << 16);
    o.w = f2bf1(b.z) | (f2bf1(b.w) << 16);
    return o;
}

// swizzled LDS fragment read: row-major [R][64] ushort tile, 16B chunk XOR'd by row&7
__device__ __forceinline__ bf16x8 lds_swz(const ushort* L, int row, int kof) {
    return *(const bf16x8*)&L[row * 64 + ((((kof >> 3) ^ row) & 7) << 3)];
}

// ---------------- router: one wave per token; also emits x in bf16 ----------------
__global__ void __launch_bounds__(256) k_router(
    const float* __restrict__ x, const float* __restrict__ Wr,
    const float* __restrict__ br, int* __restrict__ counts,
    int* __restrict__ tok_e, float* __restrict__ tok_w,
    ushort* __restrict__ xb) {
    int wave = blockIdx.x * 4 + (threadIdx.x >> 6);
    int lane = threadIdx.x & 63;
    const float4* row = (const float4*)(x + (size_t)wave * CDIM);
    ushort4* xrow = (ushort4*)(xb + (size_t)wave * CDIM);
    float acc[NEXP];
#pragma unroll
    for (int e = 0; e < NEXP; ++e) acc[e] = 0.f;
#pragma unroll
    for (int j = 0; j < 4; ++j) {
        float4 v = row[j * 64 + lane];
        ushort4 o;
        o.x = f2bf(v.x); o.y = f2bf(v.y); o.z = f2bf(v.z); o.w = f2bf(v.w);
        xrow[j * 64 + lane] = o;
#pragma unroll
        for (int e = 0; e < NEXP; ++e) {
            float4 w = ((const float4*)(Wr + e * CDIM))[j * 64 + lane];
            acc[e] += v.x * w.x + v.y * w.y + v.z * w.z + v.w * w.w;
        }
    }
#pragma unroll
    for (int off = 32; off > 0; off >>= 1)
#pragma unroll
        for (int e = 0; e < NEXP; ++e) acc[e] += __shfl_xor(acc[e], off, 64);
    if (lane == 0) {
        float l[NEXP];
#pragma unroll
        for (int e = 0; e < NEXP; ++e) l[e] = acc[e] + br[e];
        int i0 = 0; float l0 = l[0];
#pragma unroll
        for (int e = 1; e < NEXP; ++e) if (l[e] > l0) { l0 = l[e]; i0 = e; }
        int i1 = -1; float l1 = -1e30f;
#pragma unroll
        for (int e = 0; e < NEXP; ++e) if (e != i0 && l[e] > l1) { l1 = l[e]; i1 = e; }
        float s  = __expf(l1 - l0);   // renormalized top-2 softmax
        float w0 = 1.f / (1.f + s);
        float w1 = 1.f - w0;
        tok_e[wave * 2] = i0; tok_e[wave * 2 + 1] = i1;
        tok_w[wave * 2] = w0; tok_w[wave * 2 + 1] = w1;
        atomicAdd(&counts[i0], 1); atomicAdd(&counts[i1], 1);
    }
}

// ---------------- scatter tokens into expert-grouped slots (+ aux loss) ----------------
__global__ void __launch_bounds__(256) k_scatter(
    const int* __restrict__ tok_e, const int* __restrict__ counts,
    int* __restrict__ cursor, int* __restrict__ perm_token,
    int* __restrict__ tok_slot, float* __restrict__ out_aux) {
    int t = blockIdx.x * 256 + threadIdx.x;
    if (t >= NTOK) return;
    if (t == 0) {
        float aux = 0.f;
#pragma unroll
        for (int k = 0; k < NEXP; ++k) {
            float ld = (float)counts[k] * (1.f / (float)NTOK);
            aux += ld * ld;
        }
        *out_aux = aux;
    }
#pragma unroll
    for (int k = 0; k < 2; ++k) {
        int e = tok_e[t * 2 + k];
        int off = 0, o = 0;
#pragma unroll
        for (int j = 0; j < NEXP; ++j) {
            if (j == e) off = o;
            o += counts[j];
        }
        int pos = atomicAdd(&cursor[e], 1);
        int s = off + pos;
        perm_token[s] = t;
        tok_slot[t * 2 + k] = s;
    }
}

// ---------------- grouped GEMM1: 256 slots x 128 y-cols (dual), BK=64, dbuf ----------------
// A: bf16 xb via global_load_lds; B: fp32 Win reg-staged + f2bf + swizzled ds_write
__global__ void __launch_bounds__(512, 2) k_gemm1(
    const ushort* __restrict__ xb, const float* __restrict__ Win,
    const float* __restrict__ conv_w, const float* __restrict__ conv_b,
    const float* __restrict__ Dp, const int* __restrict__ counts,
    const int* __restrict__ perm_token, ushort* __restrict__ y) {
    int h = blockIdx.x;                  // 1280 = 8 * 160
    int vb = (h & 7) * 160 + (h >> 3);   // expert-per-XCD swizzle, bijective
    int e   = vb / 160;
    int r   = vb % 160;
    int mt0 = r >> 4;                    // 0..9
    int nt  = r & 15;                    // 0..15 over DIN/128
    int base = 0;
#pragma unroll
    for (int k = 0; k < NEXP; ++k) if (k < e) base += counts[k];
    int cnt = counts[e];
    if (cnt == 0) return;
    int mtiles = (cnt + 255) >> 8;
    int n0 = nt * 128;

    __shared__ ushort aL[2][256 * 64];   // 2 x 32 KB
    __shared__ ushort bL[2][256 * 64];   // 2 x 32 KB (128 xi rows + 128 z rows)

    int tid = threadIdx.x, lane = tid & 63, w = tid >> 6;
    int Mw = w >> 1, Nw = w & 1;         // wave tile: 64 slots x 64 y-cols (dual)
    const float* WinE = Win + (size_t)e * (2 * DIN) * CDIM;
    int schunk = ((tid & 7) ^ ((tid >> 3) & 7)) << 3;   // pre-swizzled A source chunk

    // B staging geometry: thread owns half a row (32 elems = 8 float4)
    int brow = tid >> 1;                 // 0..255
    int bcb  = (tid & 1) * 32;           // col base (elems)
    int bgrow = (brow < 128) ? (n0 + brow) : (DIN + n0 + (brow - 128));
    uint bsrc = (uint)bgrow * CDIM + bcb;        // fp32 element offset
    // swizzled LDS dst chunks: jc = (tid&1)*4 + w2, phys = jc ^ (brow&7)
    uint bdst[4];
#pragma unroll
    for (int w2 = 0; w2 < 4; ++w2) {
        int jc = (tid & 1) * 4 + w2;
        bdst[w2] = brow * 64 + ((jc ^ (brow & 7)) << 3);
    }

    for (int mt = mt0; mt < mtiles; mt += 10) {
        int rem = cnt - mt * 256;
        uint asrc[4];
#pragma unroll
        for (int i = 0; i < 4; ++i) {
            int rr = i * 64 + (tid >> 3);
            int sidx = base + mt * 256 + (rr < rem ? rr : 0);
            asrc[i] = (uint)perm_token[sidx] * CDIM + schunk;
        }

        f32x4 accXi[4][4], accZ[4][4];
#pragma unroll
        for (int m = 0; m < 4; ++m)
#pragma unroll
            for (int n = 0; n < 4; ++n) {
                accXi[m][n] = f32x4{0.f, 0.f, 0.f, 0.f};
                accZ[m][n]  = f32x4{0.f, 0.f, 0.f, 0.f};
            }

        float4 v[8];
        auto loadB = [&](int ko) {
            const float4* s = (const float4*)(WinE + bsrc + ko);
#pragma unroll
            for (int u = 0; u < 8; ++u) v[u] = s[u];
        };
        auto writeB = [&](int bi) {
#pragma unroll
            for (int w2 = 0; w2 < 4; ++w2)
                *(uint4*)&bL[bi][bdst[w2]] = pack8(v[2 * w2], v[2 * w2 + 1]);
        };
        auto stgA = [&](int bi, int ko) {
            gload_lds16(xb + asrc[0] + ko, &aL[bi][(0 * 512 + tid) * 8]);
            gload_lds16(xb + asrc[1] + ko, &aL[bi][(1 * 512 + tid) * 8]);
            gload_lds16(xb + asrc[2] + ko, &aL[bi][(2 * 512 + tid) * 8]);
            gload_lds16(xb + asrc[3] + ko, &aL[bi][(3 * 512 + tid) * 8]);
        };
        auto compute = [&](int bi) {
            const ushort* A = aL[bi];
            const ushort* B = bL[bi];
#pragma unroll
            for (int kk = 0; kk < 64; kk += 32) {
                int kof = kk + (lane >> 4) * 8;
                bf16x8 af[4], bx[4], bz[4];
#pragma unroll
                for (int m = 0; m < 4; ++m)
                    af[m] = lds_swz(A, Mw * 64 + m * 16 + (lane & 15), kof);
#pragma unroll
                for (int n = 0; n < 4; ++n) {
                    int cl = Nw * 64 + n * 16 + (lane & 15);
                    bx[n] = lds_swz(B, cl, kof);
                    bz[n] = lds_swz(B, 128 + cl, kof);
                }
                __builtin_amdgcn_s_setprio(1);
#pragma unroll
                for (int m = 0; m < 4; ++m)
#pragma unroll
                    for (int n = 0; n < 4; ++n) {
                        accXi[m][n] = __builtin_amdgcn_mfma_f32_16x16x32_bf16(af[m], bx[n], accXi[m][n], 0, 0, 0);
                        accZ[m][n]  = __builtin_amdgcn_mfma_f32_16x16x32_bf16(af[m], bz[n],  accZ[m][n],  0, 0, 0);
                    }
                __builtin_amdgcn_s_setprio(0);
            }
        };

        // prologue: K-tile 0 into buffers 0
        loadB(0);
        stgA(0, 0);
        writeB(0);
        __syncthreads();
#pragma unroll 2
        for (int kt = 0; kt < 16; ++kt) {
            int cur = kt & 1, nxt = cur ^ 1;
            bool st = kt < 15;
            int ko = (kt + 1) * 64;
            if (st) { loadB(ko); stgA(nxt, ko); }   // issue early: latency under compute
            compute(cur);
            if (st) writeB(nxt);                     // loads returned during compute
            __syncthreads();                         // drains A-gloads + B-writes; WAR
        }

        // epilogue: gated activation -> y (bf16)
#pragma unroll
        for (int n = 0; n < 4; ++n) {
            int c = n0 + Nw * 64 + n * 16 + (lane & 15);
            float cwl = conv_w[((size_t)e * DIN + c) * 4 + 3];
            float cb  = conv_b[(size_t)e * DIN + c];
            float dp  = Dp[(size_t)e * DIN + c];
#pragma unroll
            for (int m = 0; m < 4; ++m)
#pragma unroll
                for (int q = 0; q < 4; ++q) {
                    int rl = Mw * 64 + m * 16 + (lane >> 4) * 4 + q;
                    if (rl < rem) {
                        int slot = base + mt * 256 + rl;
                        float xi = accXi[m][n][q], z = accZ[m][n][q];
                        float yv = silu_f(xi * cwl + cb) * dp * silu_f(z);
                        y[(size_t)slot * DIN + c] = f2bf(yv);
                    }
                }
        }
        __syncthreads();
    }
}

// ---------------- grouped GEMM2: 256 slots x 128 out-cols, BK=64, single-buffer ----------------
// A: bf16 y via global_load_lds; B: fp32 Wout reg-staged + f2bf + swizzled ds_write
__global__ void __launch_bounds__(512, 4) k_gemm2(
    const ushort* __restrict__ y, const float* __restrict__ Wout,
    const int* __restrict__ counts, ushort* __restrict__ so) {
    __shared__ ushort aL[256 * 64];   // 32 KB (y slots)
    __shared__ ushort bL[128 * 64];   // 16 KB (Wout rows = out cols)

    int tid = threadIdx.x, lane = tid & 63, w = tid >> 6;
    int Mw = w >> 1, Nw = w & 1;      // wave tile: 64 slots x 64 cols
    int schunk = ((tid & 7) ^ ((tid >> 3) & 7)) << 3;

    int cn[NEXP];
#pragma unroll
    for (int k = 0; k < NEXP; ++k) cn[k] = counts[k];
    int tot_mtiles = 0;
#pragma unroll
    for (int k = 0; k < NEXP; ++k) tot_mtiles += (cn[k] + 255) >> 8;
    int ntiles = tot_mtiles * 8;      // x 8 n-tiles
    int b = blockIdx.x;
    int virt = (b & 7) * 64 + (b >> 3);   // XCD-chunk swizzle, 512 = 8*64

    // B staging geometry: thread owns quarter-row (16 elems = 4 float4)
    int brow = tid >> 2;              // 0..127
    int bcb  = (tid & 3) * 16;        // col base (elems)
    uint bdst[2];
#pragma unroll
    for (int w2 = 0; w2 < 2; ++w2) {
        int jc = (tid & 3) * 2 + w2;
        bdst[w2] = brow * 64 + ((jc ^ (brow & 7)) << 3);
    }

    for (int t = virt; t < ntiles; t += 512) {
        int pair = t >> 3, nt = t & 7;
        int e = 0, mt = pair, base = 0, cnt = cn[0];
        {
            int o = 0, tp = 0;
#pragma unroll
            for (int k = 0; k < NEXP; ++k) {
                int ck = cn[k];
                int tk = (ck + 255) >> 8;
                if (pair >= tp) { e = k; mt = pair - tp; base = o; cnt = ck; }
                o += ck; tp += tk;
            }
        }
        int rem = cnt - mt * 256;
        int c0 = nt * 128;
        const float* WoutE = Wout + (size_t)e * CDIM * DIN;
        uint bsrc = (uint)(c0 + brow) * DIN + bcb;   // fp32 element offset

        uint asrc[4];
#pragma unroll
        for (int i = 0; i < 4; ++i) {
            int rr = i * 64 + (tid >> 3);
            int slot = base + mt * 256 + (rr < rem ? rr : 0);
            asrc[i] = (uint)slot * DIN + schunk;
        }

        f32x4 acc[4][4];
#pragma unroll
        for (int m = 0; m < 4; ++m)
#pragma unroll
            for (int n = 0; n < 4; ++n) acc[m][n] = f32x4{0.f, 0.f, 0.f, 0.f};

#pragma unroll 1
        for (int kt = 0; kt < 32; ++kt) {
            int ko = kt * 64;
            // issue B fp32 loads first (latency), then A gloads
            float4 v[4];
            const float4* s = (const float4*)(WoutE + bsrc + ko);
#pragma unroll
            for (int u = 0; u < 4; ++u) v[u] = s[u];
            gload_lds16(y + asrc[0] + ko, &aL[(0 * 512 + tid) * 8]);
            gload_lds16(y + asrc[1] + ko, &aL[(1 * 512 + tid) * 8]);
            gload_lds16(y + asrc[2] + ko, &aL[(2 * 512 + tid) * 8]);
            gload_lds16(y + asrc[3] + ko, &aL[(3 * 512 + tid) * 8]);
#pragma unroll
            for (int w2 = 0; w2 < 2; ++w2)
                *(uint4*)&bL[bdst[w2]] = pack8(v[2 * w2], v[2 * w2 + 1]);
            __syncthreads();
#pragma unroll
            for (int kk = 0; kk < 64; kk += 32) {
                int kof = kk + (lane >> 4) * 8;
                bf16x8 af[4], bf[4];
#pragma unroll
                for (int m = 0; m < 4; ++m)
                    af[m] = lds_swz(aL, Mw * 64 + m * 16 + (lane & 15), kof);
#pragma unroll
                for (int n = 0; n < 4; ++n)
                    bf[n] = lds_swz(bL, Nw * 64 + n * 16 + (lane & 15), kof);
                __builtin_amdgcn_s_setprio(1);
#pragma unroll
                for (int m = 0; m < 4; ++m)
#pragma unroll
                    for (int n = 0; n < 4; ++n)
                        acc[m][n] = __builtin_amdgcn_mfma_f32_16x16x32_bf16(af[m], bf[n], acc[m][n], 0, 0, 0);
                __builtin_amdgcn_s_setprio(0);
            }
            __syncthreads();
        }

        // epilogue: per-slot bf16 store (combined later)
#pragma unroll
        for (int m = 0; m < 4; ++m)
#pragma unroll
            for (int q = 0; q < 4; ++q) {
                int rl = Mw * 64 + m * 16 + (lane >> 4) * 4 + q;
                if (rl < rem) {
                    int slot = base + mt * 256 + rl;
#pragma unroll
                    for (int n = 0; n < 4; ++n) {
                        int col = c0 + Nw * 64 + n * 16 + (lane & 15);
                        so[(size_t)slot * CDIM + col] = f2bf(acc[m][n][q]);
                    }
                }
            }
        __syncthreads();
    }
}

// ---------------- combine: out[t] = w0*so[s0] + w1*so[s1] ----------------
__global__ void __launch_bounds__(256) k_combine(
    const ushort* __restrict__ so, const int* __restrict__ tok_slot,
    const float* __restrict__ tok_w, float* __restrict__ out) {
    int i = blockIdx.x * 256 + threadIdx.x;   // NTOK*128 threads
    int t  = i >> 7;
    int c8 = (i & 127) << 3;
    int s0 = tok_slot[t * 2], s1 = tok_slot[t * 2 + 1];
    float w0 = tok_w[t * 2],  w1 = tok_w[t * 2 + 1];
    uint4 a = *(const uint4*)(so + (size_t)s0 * CDIM + c8);
    uint4 b = *(const uint4*)(so + (size_t)s1 * CDIM + c8);
    const ushort* au = (const ushort*)&a;
    const ushort* bu = (const ushort*)&b;
    float4 o0, o1;
    o0.x = w0 * bf2f(au[0]) + w1 * bf2f(bu[0]);
    o0.y = w0 * bf2f(au[1]) + w1 * bf2f(bu[1]);
    o0.z = w0 * bf2f(au[2]) + w1 * bf2f(bu[2]);
    o0.w = w0 * bf2f(au[3]) + w1 * bf2f(bu[3]);
    o1.x = w0 * bf2f(au[4]) + w1 * bf2f(bu[4]);
    o1.y = w0 * bf2f(au[5]) + w1 * bf2f(bu[5]);
    o1.z = w0 * bf2f(au[6]) + w1 * bf2f(bu[6]);
    o1.w = w0 * bf2f(au[7]) + w1 * bf2f(bu[7]);
    float4* dst = (float4*)(out + (size_t)t * CDIM + c8);
    dst[0] = o0; dst[1] = o1;
}

extern "C" void kernel_launch(void* const* d_in, const int* in_sizes, int n_in,
                              void* d_out, int out_size, void* d_ws, size_t ws_size,
                              hipStream_t stream) {
    const float* x      = (const float*)d_in[0];
    const float* Wr     = (const float*)d_in[1];
    const float* br     = (const float*)d_in[2];
    const float* Win    = (const float*)d_in[3];
    const float* conv_w = (const float*)d_in[4];
    const float* conv_b = (const float*)d_in[5];
    const float* Dp     = (const float*)d_in[6];
    const float* Wout   = (const float*)d_in[7];
    float* out = (float*)d_out;

    char* ws = (char*)d_ws;
    int*    counts     = (int*)(ws + 0);
    int*    cursor     = (int*)(ws + 128);
    int*    tok_e      = (int*)(ws + 4096);
    float*  tok_w      = (float*)(ws + 4096 + 1 * 65536);
    int*    perm_token = (int*)(ws + 4096 + 2 * 65536);
    int*    tok_slot   = (int*)(ws + 4096 + 3 * 65536);
    const size_t MB = 1u << 20;
    ushort* y  = (ushort*)(ws + MB);                   // 64 MB
    ushort* xb = (ushort*)(ws + MB + 67108864);        // 16 MB
    ushort* so = (ushort*)(ws + MB + 67108864 + 16777216);  // 32 MB

    hipMemsetAsync(ws, 0, 256, stream);

    k_router<<<NTOK / 4, 256, 0, stream>>>(x, Wr, br, counts, tok_e, tok_w, xb);
    k_scatter<<<NTOK / 256, 256, 0, stream>>>(tok_e, counts, cursor, perm_token,
                                              tok_slot, out + (size_t)NTOK * CDIM);

    k_gemm1<<<NEXP * 160, 512, 0, stream>>>(xb, Win, conv_w, conv_b, Dp,
                                            counts, perm_token, y);
    k_gemm2<<<512, 512, 0, stream>>>(y, Wout, counts, so);
    k_combine<<<NTOK * 128 / 256, 256, 0, stream>>>(so, tok_slot, tok_w, out);
}

// Round 18
// 626.237 us; speedup vs baseline: 1.4339x; 1.4339x over previous
//
#include <hip/hip_runtime.h>
#include <hip/hip_bf16.h>
#include <stdint.h>

#define NTOK 8192
#define CDIM 1024
#define DIN  2048
#define NEXP 8
#define NSLOT (NTOK * 2)

typedef __bf16 bf16x8 __attribute__((ext_vector_type(8)));
typedef float  f32x4  __attribute__((ext_vector_type(4)));

typedef __attribute__((address_space(1))) const unsigned char GBUF;
typedef __attribute__((address_space(3))) unsigned char LBUF;

__device__ __forceinline__ void gload_lds16(const void* g, void* l) {
    __builtin_amdgcn_global_load_lds((GBUF*)g, (LBUF*)l, 16, 0, 0);
}

__device__ __forceinline__ unsigned f2bf1(float f) {
    union { float f; unsigned u; } v; v.f = f;
    unsigned u = v.u;
    u += 0x7fffu + ((u >> 16) & 1u);   // RNE
    return u >> 16;
}
__device__ __forceinline__ ushort f2bf(float f) { return (ushort)f2bf1(f); }
__device__ __forceinline__ float bf2f(ushort u) {
    union { float f; unsigned u; } v; v.u = ((unsigned)u) << 16; return v.f;
}
__device__ __forceinline__ float silu_f(float x) { return x / (1.f + __expf(-x)); }

// pack two float4 into 8 bf16 (16 B)
__device__ __forceinline__ uint4 pack8(float4 a, float4 b) {
    uint4 o;
    o.x = f2bf1(a.x) | (f2bf1(a.y) << 16);
    o.y = f2bf1(a.z) | (f2bf1(a.w) << 16);
    o.z = f2bf1(b.x) | (f2bf1(b.y) << 16);
    o.w = f2bf1(b.z) | (f2bf1(b.w) << 16);
    return o;
}

// swizzled LDS fragment read: row-major [R][64] ushort tile, 16B chunk XOR'd by row&7
__device__ __forceinline__ bf16x8 lds_swz(const ushort* L, int row, int kof) {
    return *(const bf16x8*)&L[row * 64 + ((((kof >> 3) ^ row) & 7) << 3)];
}

// counted vmcnt wait: memory clobber pins vmem/ds ordering, MFMA/VALU stay free
#define WAITV(N) asm volatile("s_waitcnt vmcnt(" #N ")" ::: "memory")
#define BARR     __builtin_amdgcn_s_barrier()

// ---------------- fp32 -> bf16 weight convert: 16 B stores, 4-deep pipeline ----------------
// grid 2048x256; Win: 4,194,304 uint4 out = 8*STR (2 outer x 4-deep); Wout: 4*STR (1 x 4-deep)
__global__ void __launch_bounds__(256) k_cvt2(
    const float* __restrict__ Win, ushort* __restrict__ winb,
    const float* __restrict__ Wout, ushort* __restrict__ woutb) {
    const int STR = 2048 * 256;               // 524288
    int gid = blockIdx.x * 256 + threadIdx.x;
    {
        const float4* s = (const float4*)Win;
        uint4* d = (uint4*)winb;
#pragma unroll 1
        for (int o = 0; o < 2; ++o) {
            int base = o * 4 * STR + gid;
            float4 va[4], vb[4];
#pragma unroll
            for (int u = 0; u < 4; ++u) {
                va[u] = s[2 * (base + u * STR)];
                vb[u] = s[2 * (base + u * STR) + 1];
            }
#pragma unroll
            for (int u = 0; u < 4; ++u)
                d[base + u * STR] = pack8(va[u], vb[u]);
        }
    }
    {
        const float4* s = (const float4*)Wout;
        uint4* d = (uint4*)woutb;
        float4 va[4], vb[4];
#pragma unroll
        for (int u = 0; u < 4; ++u) {
            va[u] = s[2 * (gid + u * STR)];
            vb[u] = s[2 * (gid + u * STR) + 1];
        }
#pragma unroll
        for (int u = 0; u < 4; ++u)
            d[gid + u * STR] = pack8(va[u], vb[u]);
    }
}

// ---------------- router: one wave per token; also emits x in bf16 ----------------
__global__ void __launch_bounds__(256) k_router(
    const float* __restrict__ x, const float* __restrict__ Wr,
    const float* __restrict__ br, int* __restrict__ counts,
    int* __restrict__ tok_e, float* __restrict__ tok_w,
    ushort* __restrict__ xb) {
    int wave = blockIdx.x * 4 + (threadIdx.x >> 6);
    int lane = threadIdx.x & 63;
    const float4* row = (const float4*)(x + (size_t)wave * CDIM);
    ushort4* xrow = (ushort4*)(xb + (size_t)wave * CDIM);
    float acc[NEXP];
#pragma unroll
    for (int e = 0; e < NEXP; ++e) acc[e] = 0.f;
#pragma unroll
    for (int j = 0; j < 4; ++j) {
        float4 v = row[j * 64 + lane];
        ushort4 o;
        o.x = f2bf(v.x); o.y = f2bf(v.y); o.z = f2bf(v.z); o.w = f2bf(v.w);
        xrow[j * 64 + lane] = o;
#pragma unroll
        for (int e = 0; e < NEXP; ++e) {
            float4 w = ((const float4*)(Wr + e * CDIM))[j * 64 + lane];
            acc[e] += v.x * w.x + v.y * w.y + v.z * w.z + v.w * w.w;
        }
    }
#pragma unroll
    for (int off = 32; off > 0; off >>= 1)
#pragma unroll
        for (int e = 0; e < NEXP; ++e) acc[e] += __shfl_xor(acc[e], off, 64);
    if (lane == 0) {
        float l[NEXP];
#pragma unroll
        for (int e = 0; e < NEXP; ++e) l[e] = acc[e] + br[e];
        int i0 = 0; float l0 = l[0];
#pragma unroll
        for (int e = 1; e < NEXP; ++e) if (l[e] > l0) { l0 = l[e]; i0 = e; }
        int i1 = -1; float l1 = -1e30f;
#pragma unroll
        for (int e = 0; e < NEXP; ++e) if (e != i0 && l[e] > l1) { l1 = l[e]; i1 = e; }
        float s  = __expf(l1 - l0);   // renormalized top-2 softmax
        float w0 = 1.f / (1.f + s);
        float w1 = 1.f - w0;
        tok_e[wave * 2] = i0; tok_e[wave * 2 + 1] = i1;
        tok_w[wave * 2] = w0; tok_w[wave * 2 + 1] = w1;
        atomicAdd(&counts[i0], 1); atomicAdd(&counts[i1], 1);
    }
}

// ---------------- scatter tokens into expert-grouped slots (+ aux loss) ----------------
__global__ void __launch_bounds__(256) k_scatter(
    const int* __restrict__ tok_e, const int* __restrict__ counts,
    int* __restrict__ cursor, int* __restrict__ perm_token,
    int* __restrict__ tok_slot, float* __restrict__ out_aux) {
    int t = blockIdx.x * 256 + threadIdx.x;
    if (t >= NTOK) return;
    if (t == 0) {
        float aux = 0.f;
#pragma unroll
        for (int k = 0; k < NEXP; ++k) {
            float ld = (float)counts[k] * (1.f / (float)NTOK);
            aux += ld * ld;
        }
        *out_aux = aux;
    }
#pragma unroll
    for (int k = 0; k < 2; ++k) {
        int e = tok_e[t * 2 + k];
        int off = 0, o = 0;
#pragma unroll
        for (int j = 0; j < NEXP; ++j) {
            if (j == e) off = o;
            o += counts[j];
        }
        int pos = atomicAdd(&cursor[e], 1);
        int s = off + pos;
        perm_token[s] = t;
        tok_slot[t * 2 + k] = s;
    }
}

// ---------------- grouped GEMM1: 256 slots x 128 y-cols (dual), BK=64 ----------------
// 4-phase/K-tile counted-vmcnt pipeline: stage half-tile per phase, wait depth = 1 K-tile
__global__ void __launch_bounds__(512, 2) k_gemm1(
    const ushort* __restrict__ xb, const ushort* __restrict__ Winb,
    const float* __restrict__ conv_w, const float* __restrict__ conv_b,
    const float* __restrict__ Dp, const int* __restrict__ counts,
    const int* __restrict__ perm_token, ushort* __restrict__ y) {
    int h = blockIdx.x;                  // 1280 = 8 * 160
    int vb = (h & 7) * 160 + (h >> 3);   // expert-per-XCD swizzle, bijective
    int e   = vb / 160;
    int r   = vb % 160;
    int mt0 = r >> 4;                    // 0..9
    int nt  = r & 15;                    // 0..15 over DIN/128
    int base = 0;
#pragma unroll
    for (int k = 0; k < NEXP; ++k) if (k < e) base += counts[k];
    int cnt = counts[e];
    if (cnt == 0) return;
    int mtiles = (cnt + 255) >> 8;
    int n0 = nt * 128;

    __shared__ ushort aL[2][256 * 64];   // 2 x 32 KB
    __shared__ ushort bL[2][256 * 64];   // 2 x 32 KB (128 xi rows + 128 z rows)

    int tid = threadIdx.x, lane = tid & 63, w = tid >> 6;
    int Mw = w >> 1, Nw = w & 1;         // wave tile: 64 slots x 64 y-cols (dual)
    const ushort* WinE = Winb + (size_t)e * (2 * DIN) * CDIM;
    int schunk = ((tid & 7) ^ ((tid >> 3) & 7)) << 3;   // pre-swizzled source chunk

    uint bsrc[4];
#pragma unroll
    for (int i = 0; i < 4; ++i) {
        int rr = i * 64 + (tid >> 3);    // 0..255
        int grow = (rr < 128) ? (n0 + rr) : (DIN + n0 + (rr - 128));
        bsrc[i] = (uint)grow * CDIM + schunk;
    }

    for (int mt = mt0; mt < mtiles; mt += 10) {
        int rem = cnt - mt * 256;
        uint asrc[4];
#pragma unroll
        for (int i = 0; i < 4; ++i) {
            int rr = i * 64 + (tid >> 3);
            int sidx = base + mt * 256 + (rr < rem ? rr : 0);
            asrc[i] = (uint)perm_token[sidx] * CDIM + schunk;
        }

        f32x4 accXi[4][4], accZ[4][4];
#pragma unroll
        for (int m = 0; m < 4; ++m)
#pragma unroll
            for (int n = 0; n < 4; ++n) {
                accXi[m][n] = f32x4{0.f, 0.f, 0.f, 0.f};
                accZ[m][n]  = f32x4{0.f, 0.f, 0.f, 0.f};
            }

        // staging: half-tile = 2 gloads (rows i*64 pair)
        auto stgA = [&](int bi, int ko, int i, int j) {
            gload_lds16(xb + asrc[i] + ko, &aL[bi][(i * 512 + tid) * 8]);
            gload_lds16(xb + asrc[j] + ko, &aL[bi][(j * 512 + tid) * 8]);
        };
        auto stgB = [&](int bi, int ko, int i, int j) {
            gload_lds16(WinE + bsrc[i] + ko, &bL[bi][(i * 512 + tid) * 8]);
            gload_lds16(WinE + bsrc[j] + ko, &bL[bi][(j * 512 + tid) * 8]);
        };

        bf16x8 af0[4], af1[4], bx[4], bz[4];
        // prologue: stage K-tile 0 into buf 0 (stage order: A0,A1,Bxi,Bz)
        stgA(0, 0, 0, 1); stgA(0, 0, 2, 3); stgB(0, 0, 0, 1); stgB(0, 0, 2, 3);

#pragma unroll 1
        for (int kt = 0; kt < 16; ++kt) {
            int cur = kt & 1, nxt = cur ^ 1;
            const ushort* A = aL[cur];
            const ushort* B = bL[cur];
            int ko = (kt + 1) * 64;
            bool st = kt < 15;
            // ---- ph0: xi kk0 (needs A0,A1,Bxi = oldest 6 of 8) ----
            WAITV(2);
            BARR;
#pragma unroll
            for (int m = 0; m < 4; ++m)
                af0[m] = lds_swz(A, Mw * 64 + m * 16 + (lane & 15), (lane >> 4) * 8);
#pragma unroll
            for (int n = 0; n < 4; ++n)
                bx[n] = lds_swz(B, Nw * 64 + n * 16 + (lane & 15), (lane >> 4) * 8);
            if (st) stgA(nxt, ko, 0, 1);
            __builtin_amdgcn_s_setprio(1);
#pragma unroll
            for (int m = 0; m < 4; ++m)
#pragma unroll
                for (int n = 0; n < 4; ++n)
                    accXi[m][n] = __builtin_amdgcn_mfma_f32_16x16x32_bf16(af0[m], bx[n], accXi[m][n], 0, 0, 0);
            __builtin_amdgcn_s_setprio(0);
            // ---- ph1: z kk0 (needs Bz = oldest 2 of remaining) ----
            if (st) { WAITV(2); } else { WAITV(0); }
            BARR;
#pragma unroll
            for (int n = 0; n < 4; ++n)
                bz[n] = lds_swz(B, 128 + Nw * 64 + n * 16 + (lane & 15), (lane >> 4) * 8);
            if (st) stgA(nxt, ko, 2, 3);
            __builtin_amdgcn_s_setprio(1);
#pragma unroll
            for (int m = 0; m < 4; ++m)
#pragma unroll
                for (int n = 0; n < 4; ++n)
                    accZ[m][n] = __builtin_amdgcn_mfma_f32_16x16x32_bf16(af0[m], bz[n], accZ[m][n], 0, 0, 0);
            __builtin_amdgcn_s_setprio(0);
            // ---- ph2: xi kk1 (all data already resident) ----
            BARR;
#pragma unroll
            for (int m = 0; m < 4; ++m)
                af1[m] = lds_swz(A, Mw * 64 + m * 16 + (lane & 15), 32 + (lane >> 4) * 8);
#pragma unroll
            for (int n = 0; n < 4; ++n)
                bx[n] = lds_swz(B, Nw * 64 + n * 16 + (lane & 15), 32 + (lane >> 4) * 8);
            if (st) stgB(nxt, ko, 0, 1);
            __builtin_amdgcn_s_setprio(1);
#pragma unroll
            for (int m = 0; m < 4; ++m)
#pragma unroll
                for (int n = 0; n < 4; ++n)
                    accXi[m][n] = __builtin_amdgcn_mfma_f32_16x16x32_bf16(af1[m], bx[n], accXi[m][n], 0, 0, 0);
            __builtin_amdgcn_s_setprio(0);
            // ---- ph3: z kk1 ----
            BARR;
#pragma unroll
            for (int n = 0; n < 4; ++n)
                bz[n] = lds_swz(B, 128 + Nw * 64 + n * 16 + (lane & 15), 32 + (lane >> 4) * 8);
            if (st) stgB(nxt, ko, 2, 3);
            __builtin_amdgcn_s_setprio(1);
#pragma unroll
            for (int m = 0; m < 4; ++m)
#pragma unroll
                for (int n = 0; n < 4; ++n)
                    accZ[m][n] = __builtin_amdgcn_mfma_f32_16x16x32_bf16(af1[m], bz[n], accZ[m][n], 0, 0, 0);
            __builtin_amdgcn_s_setprio(0);
        }
        __syncthreads();

        // epilogue: gated activation -> y (bf16)
#pragma unroll
        for (int n = 0; n < 4; ++n) {
            int c = n0 + Nw * 64 + n * 16 + (lane & 15);
            float cwl = conv_w[((size_t)e * DIN + c) * 4 + 3];
            float cb  = conv_b[(size_t)e * DIN + c];
            float dp  = Dp[(size_t)e * DIN + c];
#pragma unroll
            for (int m = 0; m < 4; ++m)
#pragma unroll
                for (int q = 0; q < 4; ++q) {
                    int rl = Mw * 64 + m * 16 + (lane >> 4) * 4 + q;
                    if (rl < rem) {
                        int slot = base + mt * 256 + rl;
                        float xi = accXi[m][n][q], z = accZ[m][n][q];
                        float yv = silu_f(xi * cwl + cb) * dp * silu_f(z);
                        y[(size_t)slot * DIN + c] = f2bf(yv);
                    }
                }
        }
        __syncthreads();
    }
}

// ---------------- grouped GEMM2: 256 slots x 128 out-cols, BK=64 ----------------
// single-buffer 48 KB LDS, 2 blocks/CU, flat balanced tile list (local prefix),
// writes per-slot bf16 results (no atomics; combined later)
__global__ void __launch_bounds__(512, 4) k_gemm2(
    const ushort* __restrict__ y, const ushort* __restrict__ Woutb,
    const int* __restrict__ counts, ushort* __restrict__ so) {
    __shared__ ushort aL[256 * 64];   // 32 KB (y slots)
    __shared__ ushort bL[128 * 64];   // 16 KB (Wout rows = out cols)

    int tid = threadIdx.x, lane = tid & 63, w = tid >> 6;
    int Mw = w >> 1, Nw = w & 1;      // wave tile: 64 slots x 64 cols
    int schunk = ((tid & 7) ^ ((tid >> 3) & 7)) << 3;

    int cn[NEXP];
#pragma unroll
    for (int k = 0; k < NEXP; ++k) cn[k] = counts[k];
    int tot_mtiles = 0;
#pragma unroll
    for (int k = 0; k < NEXP; ++k) tot_mtiles += (cn[k] + 255) >> 8;
    int ntiles = tot_mtiles * 8;      // x 8 n-tiles
    int b = blockIdx.x;
    int virt = (b & 7) * 64 + (b >> 3);   // XCD-chunk swizzle, 512 = 8*64

    for (int t = virt; t < ntiles; t += 512) {
        int pair = t >> 3, nt = t & 7;
        int e = 0, mt = pair, base = 0, cnt = cn[0];
        {
            int o = 0, tp = 0;
#pragma unroll
            for (int k = 0; k < NEXP; ++k) {
                int ck = cn[k];
                int tk = (ck + 255) >> 8;
                if (pair >= tp) { e = k; mt = pair - tp; base = o; cnt = ck; }
                o += ck; tp += tk;
            }
        }
        int rem = cnt - mt * 256;
        int c0 = nt * 128;
        const ushort* WoutE = Woutb + (size_t)e * CDIM * DIN;

        uint asrc[4], bsrc[2];
#pragma unroll
        for (int i = 0; i < 4; ++i) {
            int rr = i * 64 + (tid >> 3);
            int slot = base + mt * 256 + (rr < rem ? rr : 0);
            asrc[i] = (uint)slot * DIN + schunk;
        }
#pragma unroll
        for (int i = 0; i < 2; ++i) {
            int rr = i * 64 + (tid >> 3);
            bsrc[i] = (uint)(c0 + rr) * DIN + schunk;
        }

        f32x4 acc[4][4];
#pragma unroll
        for (int m = 0; m < 4; ++m)
#pragma unroll
            for (int n = 0; n < 4; ++n) acc[m][n] = f32x4{0.f, 0.f, 0.f, 0.f};

#pragma unroll 1
        for (int kt = 0; kt < 32; ++kt) {
            int ko = kt * 64;
            gload_lds16(y + asrc[0] + ko, &aL[(0 * 512 + tid) * 8]);
            gload_lds16(y + asrc[1] + ko, &aL[(1 * 512 + tid) * 8]);
            gload_lds16(y + asrc[2] + ko, &aL[(2 * 512 + tid) * 8]);
            gload_lds16(y + asrc[3] + ko, &aL[(3 * 512 + tid) * 8]);
            gload_lds16(WoutE + bsrc[0] + ko, &bL[(0 * 512 + tid) * 8]);
            gload_lds16(WoutE + bsrc[1] + ko, &bL[(1 * 512 + tid) * 8]);
            __syncthreads();
#pragma unroll
            for (int kk = 0; kk < 64; kk += 32) {
                int kof = kk + (lane >> 4) * 8;
                bf16x8 af[4], bf[4];
#pragma unroll
                for (int m = 0; m < 4; ++m)
                    af[m] = lds_swz(aL, Mw * 64 + m * 16 + (lane & 15), kof);
#pragma unroll
                for (int n = 0; n < 4; ++n)
                    bf[n] = lds_swz(bL, Nw * 64 + n * 16 + (lane & 15), kof);
                __builtin_amdgcn_s_setprio(1);
#pragma unroll
                for (int m = 0; m < 4; ++m)
#pragma unroll
                    for (int n = 0; n < 4; ++n)
                        acc[m][n] = __builtin_amdgcn_mfma_f32_16x16x32_bf16(af[m], bf[n], acc[m][n], 0, 0, 0);
                __builtin_amdgcn_s_setprio(0);
            }
            __syncthreads();
        }

        // epilogue: per-slot bf16 store (combined later)
#pragma unroll
        for (int m = 0; m < 4; ++m)
#pragma unroll
            for (int q = 0; q < 4; ++q) {
                int rl = Mw * 64 + m * 16 + (lane >> 4) * 4 + q;
                if (rl < rem) {
                    int slot = base + mt * 256 + rl;
#pragma unroll
                    for (int n = 0; n < 4; ++n) {
                        int col = c0 + Nw * 64 + n * 16 + (lane & 15);
                        so[(size_t)slot * CDIM + col] = f2bf(acc[m][n][q]);
                    }
                }
            }
        __syncthreads();
    }
}

// ---------------- combine: out[t] = w0*so[s0] + w1*so[s1] ----------------
__global__ void __launch_bounds__(256) k_combine(
    const ushort* __restrict__ so, const int* __restrict__ tok_slot,
    const float* __restrict__ tok_w, float* __restrict__ out) {
    int i = blockIdx.x * 256 + threadIdx.x;   // NTOK*128 threads
    int t  = i >> 7;
    int c8 = (i & 127) << 3;
    int s0 = tok_slot[t * 2], s1 = tok_slot[t * 2 + 1];
    float w0 = tok_w[t * 2],  w1 = tok_w[t * 2 + 1];
    uint4 a = *(const uint4*)(so + (size_t)s0 * CDIM + c8);
    uint4 b = *(const uint4*)(so + (size_t)s1 * CDIM + c8);
    const ushort* au = (const ushort*)&a;
    const ushort* bu = (const ushort*)&b;
    float4 o0, o1;
    o0.x = w0 * bf2f(au[0]) + w1 * bf2f(bu[0]);
    o0.y = w0 * bf2f(au[1]) + w1 * bf2f(bu[1]);
    o0.z = w0 * bf2f(au[2]) + w1 * bf2f(bu[2]);
    o0.w = w0 * bf2f(au[3]) + w1 * bf2f(bu[3]);
    o1.x = w0 * bf2f(au[4]) + w1 * bf2f(bu[4]);
    o1.y = w0 * bf2f(au[5]) + w1 * bf2f(bu[5]);
    o1.z = w0 * bf2f(au[6]) + w1 * bf2f(bu[6]);
    o1.w = w0 * bf2f(au[7]) + w1 * bf2f(bu[7]);
    float4* dst = (float4*)(out + (size_t)t * CDIM + c8);
    dst[0] = o0; dst[1] = o1;
}

extern "C" void kernel_launch(void* const* d_in, const int* in_sizes, int n_in,
                              void* d_out, int out_size, void* d_ws, size_t ws_size,
                              hipStream_t stream) {
    const float* x      = (const float*)d_in[0];
    const float* Wr     = (const float*)d_in[1];
    const float* br     = (const float*)d_in[2];
    const float* Win    = (const float*)d_in[3];
    const float* conv_w = (const float*)d_in[4];
    const float* conv_b = (const float*)d_in[5];
    const float* Dp     = (const float*)d_in[6];
    const float* Wout   = (const float*)d_in[7];
    float* out = (float*)d_out;

    char* ws = (char*)d_ws;
    int*    counts     = (int*)(ws + 0);
    int*    cursor     = (int*)(ws + 128);
    int*    tok_e      = (int*)(ws + 4096);
    float*  tok_w      = (float*)(ws + 4096 + 1 * 65536);
    int*    perm_token = (int*)(ws + 4096 + 2 * 65536);
    int*    tok_slot   = (int*)(ws + 4096 + 3 * 65536);
    const size_t MB = 1u << 20;
    ushort* y     = (ushort*)(ws + MB);                               // 64 MB
    ushort* xb    = (ushort*)(ws + MB + 67108864);                    // 16 MB
    ushort* winb  = (ushort*)(ws + MB + 67108864 + 16777216);         // 64 MB
    ushort* woutb = (ushort*)(ws + MB + 67108864 + 16777216 + 67108864); // 32 MB
    ushort* so    = winb;  // slot_out aliases winb (dead after gemm1; 33.5 MB <= 64 MB)

    hipMemsetAsync(ws, 0, 256, stream);

    k_cvt2<<<2048, 256, 0, stream>>>(Win, winb, Wout, woutb);
    k_router<<<NTOK / 4, 256, 0, stream>>>(x, Wr, br, counts, tok_e, tok_w, xb);
    k_scatter<<<NTOK / 256, 256, 0, stream>>>(tok_e, counts, cursor, perm_token,
                                              tok_slot, out + (size_t)NTOK * CDIM);

    k_gemm1<<<NEXP * 160, 512, 0, stream>>>(xb, winb, conv_w, conv_b, Dp,
                                            counts, perm_token, y);
    k_gemm2<<<512, 512, 0, stream>>>(y, woutb, counts, so);
    k_combine<<<NTOK * 128 / 256, 256, 0, stream>>>(so, tok_slot, tok_w, out);
}

// Round 19
// 620.566 us; speedup vs baseline: 1.4470x; 1.0091x over previous
//
#include <hip/hip_runtime.h>
#include <hip/hip_bf16.h>
#include <stdint.h>

#define NTOK 8192
#define CDIM 1024
#define DIN  2048
#define NEXP 8
#define NSLOT (NTOK * 2)

typedef __bf16 bf16x8 __attribute__((ext_vector_type(8)));
typedef float  f32x4  __attribute__((ext_vector_type(4)));

typedef __attribute__((address_space(1))) const unsigned char GBUF;
typedef __attribute__((address_space(3))) unsigned char LBUF;

__device__ __forceinline__ void gload_lds16(const void* g, void* l) {
    __builtin_amdgcn_global_load_lds((GBUF*)g, (LBUF*)l, 16, 0, 0);
}

__device__ __forceinline__ unsigned f2bf1(float f) {
    union { float f; unsigned u; } v; v.f = f;
    unsigned u = v.u;
    u += 0x7fffu + ((u >> 16) & 1u);   // RNE
    return u >> 16;
}
__device__ __forceinline__ ushort f2bf(float f) { return (ushort)f2bf1(f); }
__device__ __forceinline__ float bf2f(ushort u) {
    union { float f; unsigned u; } v; v.u = ((unsigned)u) << 16; return v.f;
}
__device__ __forceinline__ float silu_f(float x) { return x / (1.f + __expf(-x)); }

// pack two float4 into 8 bf16 (16 B)
__device__ __forceinline__ uint4 pack8(float4 a, float4 b) {
    uint4 o;
    o.x = f2bf1(a.x) | (f2bf1(a.y) << 16);
    o.y = f2bf1(a.z) | (f2bf1(a.w) << 16);
    o.z = f2bf1(b.x) | (f2bf1(b.y) << 16);
    o.w = f2bf1(b.z) | (f2bf1(b.w) << 16);
    return o;
}

// swizzled LDS fragment read: row-major [R][64] ushort tile, 16B chunk XOR'd by row&7
__device__ __forceinline__ bf16x8 lds_swz(const ushort* L, int row, int kof) {
    return *(const bf16x8*)&L[row * 64 + ((((kof >> 3) ^ row) & 7) << 3)];
}

// counted vmcnt wait: memory clobber pins vmem/ds ordering, MFMA/VALU stay free
#define WAITV(N) asm volatile("s_waitcnt vmcnt(" #N ")" ::: "memory")
#define BARR     __builtin_amdgcn_s_barrier()

// ---------------- fp32 -> bf16 convert: Win only (Wout is folded into gemm1) ----------------
__global__ void __launch_bounds__(256) k_cvtWin(
    const float* __restrict__ Win, ushort* __restrict__ winb) {
    const int STR = 2048 * 256;               // 524288
    int gid = blockIdx.x * 256 + threadIdx.x;
    const float4* s = (const float4*)Win;
    uint4* d = (uint4*)winb;
#pragma unroll 1
    for (int o = 0; o < 2; ++o) {             // 4,194,304 uint4 = 8*STR
        int base = o * 4 * STR + gid;
        float4 va[4], vb[4];
#pragma unroll
        for (int u = 0; u < 4; ++u) {
            va[u] = s[2 * (base + u * STR)];
            vb[u] = s[2 * (base + u * STR) + 1];
        }
#pragma unroll
        for (int u = 0; u < 4; ++u)
            d[base + u * STR] = pack8(va[u], vb[u]);
    }
}

// ---------------- router: one wave per token; also emits x in bf16 ----------------
__global__ void __launch_bounds__(256) k_router(
    const float* __restrict__ x, const float* __restrict__ Wr,
    const float* __restrict__ br, int* __restrict__ counts,
    int* __restrict__ tok_e, float* __restrict__ tok_w,
    ushort* __restrict__ xb) {
    int wave = blockIdx.x * 4 + (threadIdx.x >> 6);
    int lane = threadIdx.x & 63;
    const float4* row = (const float4*)(x + (size_t)wave * CDIM);
    ushort4* xrow = (ushort4*)(xb + (size_t)wave * CDIM);
    float acc[NEXP];
#pragma unroll
    for (int e = 0; e < NEXP; ++e) acc[e] = 0.f;
#pragma unroll
    for (int j = 0; j < 4; ++j) {
        float4 v = row[j * 64 + lane];
        ushort4 o;
        o.x = f2bf(v.x); o.y = f2bf(v.y); o.z = f2bf(v.z); o.w = f2bf(v.w);
        xrow[j * 64 + lane] = o;
#pragma unroll
        for (int e = 0; e < NEXP; ++e) {
            float4 w = ((const float4*)(Wr + e * CDIM))[j * 64 + lane];
            acc[e] += v.x * w.x + v.y * w.y + v.z * w.z + v.w * w.w;
        }
    }
#pragma unroll
    for (int off = 32; off > 0; off >>= 1)
#pragma unroll
        for (int e = 0; e < NEXP; ++e) acc[e] += __shfl_xor(acc[e], off, 64);
    if (lane == 0) {
        float l[NEXP];
#pragma unroll
        for (int e = 0; e < NEXP; ++e) l[e] = acc[e] + br[e];
        int i0 = 0; float l0 = l[0];
#pragma unroll
        for (int e = 1; e < NEXP; ++e) if (l[e] > l0) { l0 = l[e]; i0 = e; }
        int i1 = -1; float l1 = -1e30f;
#pragma unroll
        for (int e = 0; e < NEXP; ++e) if (e != i0 && l[e] > l1) { l1 = l[e]; i1 = e; }
        float s  = __expf(l1 - l0);   // renormalized top-2 softmax
        float w0 = 1.f / (1.f + s);
        float w1 = 1.f - w0;
        tok_e[wave * 2] = i0; tok_e[wave * 2 + 1] = i1;
        tok_w[wave * 2] = w0; tok_w[wave * 2 + 1] = w1;
        atomicAdd(&counts[i0], 1); atomicAdd(&counts[i1], 1);
    }
}

// ---------------- scatter tokens into expert-grouped slots (+ aux loss) ----------------
__global__ void __launch_bounds__(256) k_scatter(
    const int* __restrict__ tok_e, const int* __restrict__ counts,
    int* __restrict__ cursor, int* __restrict__ perm_token,
    int* __restrict__ tok_slot, float* __restrict__ out_aux) {
    int t = blockIdx.x * 256 + threadIdx.x;
    if (t >= NTOK) return;
    if (t == 0) {
        float aux = 0.f;
#pragma unroll
        for (int k = 0; k < NEXP; ++k) {
            float ld = (float)counts[k] * (1.f / (float)NTOK);
            aux += ld * ld;
        }
        *out_aux = aux;
    }
#pragma unroll
    for (int k = 0; k < 2; ++k) {
        int e = tok_e[t * 2 + k];
        int off = 0, o = 0;
#pragma unroll
        for (int j = 0; j < NEXP; ++j) {
            if (j == e) off = o;
            o += counts[j];
        }
        int pos = atomicAdd(&cursor[e], 1);
        int s = off + pos;
        perm_token[s] = t;
        tok_slot[t * 2 + k] = s;
    }
}

// ---------------- grouped GEMM1: 256 slots x 128 y-cols (dual), BK=64 ----------------
// 4-phase/K-tile counted-vmcnt pipeline; post-loop: each block converts its share of
// Wout fp32->bf16 (tail-fill overlap -- stream order guarantees completion before gemm2)
__global__ void __launch_bounds__(512, 2) k_gemm1(
    const ushort* __restrict__ xb, const ushort* __restrict__ Winb,
    const float* __restrict__ conv_w, const float* __restrict__ conv_b,
    const float* __restrict__ Dp, const int* __restrict__ counts,
    const int* __restrict__ perm_token, ushort* __restrict__ y,
    const float* __restrict__ Wout, ushort* __restrict__ woutb) {
    int h = blockIdx.x;                  // 1280 = 8 * 160
    int vb = (h & 7) * 160 + (h >> 3);   // expert-per-XCD swizzle, bijective
    int e   = vb / 160;
    int r   = vb % 160;
    int mt0 = r >> 4;                    // 0..9
    int nt  = r & 15;                    // 0..15 over DIN/128
    int base = 0;
#pragma unroll
    for (int k = 0; k < NEXP; ++k) if (k < e) base += counts[k];
    int cnt = counts[e];
    int mtiles = (cnt + 255) >> 8;
    int n0 = nt * 128;

    __shared__ ushort aL[2][256 * 64];   // 2 x 32 KB
    __shared__ ushort bL[2][256 * 64];   // 2 x 32 KB (128 xi rows + 128 z rows)

    int tid = threadIdx.x, lane = tid & 63, w = tid >> 6;
    int Mw = w >> 1, Nw = w & 1;         // wave tile: 64 slots x 64 y-cols (dual)
    const ushort* WinE = Winb + (size_t)e * (2 * DIN) * CDIM;
    int schunk = ((tid & 7) ^ ((tid >> 3) & 7)) << 3;   // pre-swizzled source chunk

    uint bsrc[4];
#pragma unroll
    for (int i = 0; i < 4; ++i) {
        int rr = i * 64 + (tid >> 3);    // 0..255
        int grow = (rr < 128) ? (n0 + rr) : (DIN + n0 + (rr - 128));
        bsrc[i] = (uint)grow * CDIM + schunk;
    }

    for (int mt = mt0; mt < mtiles; mt += 10) {
        int rem = cnt - mt * 256;
        uint asrc[4];
#pragma unroll
        for (int i = 0; i < 4; ++i) {
            int rr = i * 64 + (tid >> 3);
            int sidx = base + mt * 256 + (rr < rem ? rr : 0);
            asrc[i] = (uint)perm_token[sidx] * CDIM + schunk;
        }

        f32x4 accXi[4][4], accZ[4][4];
#pragma unroll
        for (int m = 0; m < 4; ++m)
#pragma unroll
            for (int n = 0; n < 4; ++n) {
                accXi[m][n] = f32x4{0.f, 0.f, 0.f, 0.f};
                accZ[m][n]  = f32x4{0.f, 0.f, 0.f, 0.f};
            }

        // staging: half-tile = 2 gloads (rows i*64 pair)
        auto stgA = [&](int bi, int ko, int i, int j) {
            gload_lds16(xb + asrc[i] + ko, &aL[bi][(i * 512 + tid) * 8]);
            gload_lds16(xb + asrc[j] + ko, &aL[bi][(j * 512 + tid) * 8]);
        };
        auto stgB = [&](int bi, int ko, int i, int j) {
            gload_lds16(WinE + bsrc[i] + ko, &bL[bi][(i * 512 + tid) * 8]);
            gload_lds16(WinE + bsrc[j] + ko, &bL[bi][(j * 512 + tid) * 8]);
        };

        bf16x8 af0[4], af1[4], bx[4], bz[4];
        // prologue: stage K-tile 0 into buf 0 (stage order: A0,A1,Bxi,Bz)
        stgA(0, 0, 0, 1); stgA(0, 0, 2, 3); stgB(0, 0, 0, 1); stgB(0, 0, 2, 3);

#pragma unroll 1
        for (int kt = 0; kt < 16; ++kt) {
            int cur = kt & 1, nxt = cur ^ 1;
            const ushort* A = aL[cur];
            const ushort* B = bL[cur];
            int ko = (kt + 1) * 64;
            bool st = kt < 15;
            // ---- ph0: xi kk0 (needs A0,A1,Bxi = oldest 6 of 8) ----
            WAITV(2);
            BARR;
#pragma unroll
            for (int m = 0; m < 4; ++m)
                af0[m] = lds_swz(A, Mw * 64 + m * 16 + (lane & 15), (lane >> 4) * 8);
#pragma unroll
            for (int n = 0; n < 4; ++n)
                bx[n] = lds_swz(B, Nw * 64 + n * 16 + (lane & 15), (lane >> 4) * 8);
            if (st) stgA(nxt, ko, 0, 1);
            __builtin_amdgcn_s_setprio(1);
#pragma unroll
            for (int m = 0; m < 4; ++m)
#pragma unroll
                for (int n = 0; n < 4; ++n)
                    accXi[m][n] = __builtin_amdgcn_mfma_f32_16x16x32_bf16(af0[m], bx[n], accXi[m][n], 0, 0, 0);
            __builtin_amdgcn_s_setprio(0);
            // ---- ph1: z kk0 (needs Bz = oldest 2 of remaining) ----
            if (st) { WAITV(2); } else { WAITV(0); }
            BARR;
#pragma unroll
            for (int n = 0; n < 4; ++n)
                bz[n] = lds_swz(B, 128 + Nw * 64 + n * 16 + (lane & 15), (lane >> 4) * 8);
            if (st) stgA(nxt, ko, 2, 3);
            __builtin_amdgcn_s_setprio(1);
#pragma unroll
            for (int m = 0; m < 4; ++m)
#pragma unroll
                for (int n = 0; n < 4; ++n)
                    accZ[m][n] = __builtin_amdgcn_mfma_f32_16x16x32_bf16(af0[m], bz[n], accZ[m][n], 0, 0, 0);
            __builtin_amdgcn_s_setprio(0);
            // ---- ph2: xi kk1 (all data already resident) ----
            BARR;
#pragma unroll
            for (int m = 0; m < 4; ++m)
                af1[m] = lds_swz(A, Mw * 64 + m * 16 + (lane & 15), 32 + (lane >> 4) * 8);
#pragma unroll
            for (int n = 0; n < 4; ++n)
                bx[n] = lds_swz(B, Nw * 64 + n * 16 + (lane & 15), 32 + (lane >> 4) * 8);
            if (st) stgB(nxt, ko, 0, 1);
            __builtin_amdgcn_s_setprio(1);
#pragma unroll
            for (int m = 0; m < 4; ++m)
#pragma unroll
                for (int n = 0; n < 4; ++n)
                    accXi[m][n] = __builtin_amdgcn_mfma_f32_16x16x32_bf16(af1[m], bx[n], accXi[m][n], 0, 0, 0);
            __builtin_amdgcn_s_setprio(0);
            // ---- ph3: z kk1 ----
            BARR;
#pragma unroll
            for (int n = 0; n < 4; ++n)
                bz[n] = lds_swz(B, 128 + Nw * 64 + n * 16 + (lane & 15), 32 + (lane >> 4) * 8);
            if (st) stgB(nxt, ko, 2, 3);
            __builtin_amdgcn_s_setprio(1);
#pragma unroll
            for (int m = 0; m < 4; ++m)
#pragma unroll
                for (int n = 0; n < 4; ++n)
                    accZ[m][n] = __builtin_amdgcn_mfma_f32_16x16x32_bf16(af1[m], bz[n], accZ[m][n], 0, 0, 0);
            __builtin_amdgcn_s_setprio(0);
        }
        __syncthreads();

        // epilogue: gated activation -> y (bf16)
#pragma unroll
        for (int n = 0; n < 4; ++n) {
            int c = n0 + Nw * 64 + n * 16 + (lane & 15);
            float cwl = conv_w[((size_t)e * DIN + c) * 4 + 3];
            float cb  = conv_b[(size_t)e * DIN + c];
            float dp  = Dp[(size_t)e * DIN + c];
#pragma unroll
            for (int m = 0; m < 4; ++m)
#pragma unroll
                for (int q = 0; q < 4; ++q) {
                    int rl = Mw * 64 + m * 16 + (lane >> 4) * 4 + q;
                    if (rl < rem) {
                        int slot = base + mt * 256 + rl;
                        float xi = accXi[m][n][q], z = accZ[m][n][q];
                        float yv = silu_f(xi * cwl + cb) * dp * silu_f(z);
                        y[(size_t)slot * DIN + c] = f2bf(yv);
                    }
                }
        }
        __syncthreads();
    }

    // ---- tail-fill: convert this block's share of Wout (fp32 -> bf16) ----
    // 2,097,152 uint4 outputs over 1280 blocks x 512 threads (grid-stride)
    {
        const float4* s = (const float4*)Wout;
        uint4* d = (uint4*)woutb;
        const int NOUT = NEXP * CDIM * DIN / 8;   // 2097152
        const int STRD = 1280 * 512;              // 655360
#pragma unroll 1
        for (int i = blockIdx.x * 512 + tid; i < NOUT; i += STRD) {
            float4 a = s[2 * i], bq = s[2 * i + 1];
            d[i] = pack8(a, bq);
        }
    }
}

// ---------------- grouped GEMM2: 256 slots x 128 out-cols, BK=64 ----------------
// single-buffer 48 KB LDS, 2 blocks/CU, flat balanced tile list (local prefix),
// writes per-slot bf16 results (no atomics; combined later)
__global__ void __launch_bounds__(512, 4) k_gemm2(
    const ushort* __restrict__ y, const ushort* __restrict__ Woutb,
    const int* __restrict__ counts, ushort* __restrict__ so) {
    __shared__ ushort aL[256 * 64];   // 32 KB (y slots)
    __shared__ ushort bL[128 * 64];   // 16 KB (Wout rows = out cols)

    int tid = threadIdx.x, lane = tid & 63, w = tid >> 6;
    int Mw = w >> 1, Nw = w & 1;      // wave tile: 64 slots x 64 cols
    int schunk = ((tid & 7) ^ ((tid >> 3) & 7)) << 3;

    int cn[NEXP];
#pragma unroll
    for (int k = 0; k < NEXP; ++k) cn[k] = counts[k];
    int tot_mtiles = 0;
#pragma unroll
    for (int k = 0; k < NEXP; ++k) tot_mtiles += (cn[k] + 255) >> 8;
    int ntiles = tot_mtiles * 8;      // x 8 n-tiles
    int b = blockIdx.x;
    int virt = (b & 7) * 64 + (b >> 3);   // XCD-chunk swizzle, 512 = 8*64

    for (int t = virt; t < ntiles; t += 512) {
        int pair = t >> 3, nt = t & 7;
        int e = 0, mt = pair, base = 0, cnt = cn[0];
        {
            int o = 0, tp = 0;
#pragma unroll
            for (int k = 0; k < NEXP; ++k) {
                int ck = cn[k];
                int tk = (ck + 255) >> 8;
                if (pair >= tp) { e = k; mt = pair - tp; base = o; cnt = ck; }
                o += ck; tp += tk;
            }
        }
        int rem = cnt - mt * 256;
        int c0 = nt * 128;
        const ushort* WoutE = Woutb + (size_t)e * CDIM * DIN;

        uint asrc[4], bsrc[2];
#pragma unroll
        for (int i = 0; i < 4; ++i) {
            int rr = i * 64 + (tid >> 3);
            int slot = base + mt * 256 + (rr < rem ? rr : 0);
            asrc[i] = (uint)slot * DIN + schunk;
        }
#pragma unroll
        for (int i = 0; i < 2; ++i) {
            int rr = i * 64 + (tid >> 3);
            bsrc[i] = (uint)(c0 + rr) * DIN + schunk;
        }

        f32x4 acc[4][4];
#pragma unroll
        for (int m = 0; m < 4; ++m)
#pragma unroll
            for (int n = 0; n < 4; ++n) acc[m][n] = f32x4{0.f, 0.f, 0.f, 0.f};

#pragma unroll 1
        for (int kt = 0; kt < 32; ++kt) {
            int ko = kt * 64;
            gload_lds16(y + asrc[0] + ko, &aL[(0 * 512 + tid) * 8]);
            gload_lds16(y + asrc[1] + ko, &aL[(1 * 512 + tid) * 8]);
            gload_lds16(y + asrc[2] + ko, &aL[(2 * 512 + tid) * 8]);
            gload_lds16(y + asrc[3] + ko, &aL[(3 * 512 + tid) * 8]);
            gload_lds16(WoutE + bsrc[0] + ko, &bL[(0 * 512 + tid) * 8]);
            gload_lds16(WoutE + bsrc[1] + ko, &bL[(1 * 512 + tid) * 8]);
            __syncthreads();
#pragma unroll
            for (int kk = 0; kk < 64; kk += 32) {
                int kof = kk + (lane >> 4) * 8;
                bf16x8 af[4], bf[4];
#pragma unroll
                for (int m = 0; m < 4; ++m)
                    af[m] = lds_swz(aL, Mw * 64 + m * 16 + (lane & 15), kof);
#pragma unroll
                for (int n = 0; n < 4; ++n)
                    bf[n] = lds_swz(bL, Nw * 64 + n * 16 + (lane & 15), kof);
                __builtin_amdgcn_s_setprio(1);
#pragma unroll
                for (int m = 0; m < 4; ++m)
#pragma unroll
                    for (int n = 0; n < 4; ++n)
                        acc[m][n] = __builtin_amdgcn_mfma_f32_16x16x32_bf16(af[m], bf[n], acc[m][n], 0, 0, 0);
                __builtin_amdgcn_s_setprio(0);
            }
            __syncthreads();
        }

        // epilogue: per-slot bf16 store (combined later)
#pragma unroll
        for (int m = 0; m < 4; ++m)
#pragma unroll
            for (int q = 0; q < 4; ++q) {
                int rl = Mw * 64 + m * 16 + (lane >> 4) * 4 + q;
                if (rl < rem) {
                    int slot = base + mt * 256 + rl;
#pragma unroll
                    for (int n = 0; n < 4; ++n) {
                        int col = c0 + Nw * 64 + n * 16 + (lane & 15);
                        so[(size_t)slot * CDIM + col] = f2bf(acc[m][n][q]);
                    }
                }
            }
        __syncthreads();
    }
}

// ---------------- combine: out[t] = w0*so[s0] + w1*so[s1] ----------------
__global__ void __launch_bounds__(256) k_combine(
    const ushort* __restrict__ so, const int* __restrict__ tok_slot,
    const float* __restrict__ tok_w, float* __restrict__ out) {
    int i = blockIdx.x * 256 + threadIdx.x;   // NTOK*128 threads
    int t  = i >> 7;
    int c8 = (i & 127) << 3;
    int s0 = tok_slot[t * 2], s1 = tok_slot[t * 2 + 1];
    float w0 = tok_w[t * 2],  w1 = tok_w[t * 2 + 1];
    uint4 a = *(const uint4*)(so + (size_t)s0 * CDIM + c8);
    uint4 b = *(const uint4*)(so + (size_t)s1 * CDIM + c8);
    const ushort* au = (const ushort*)&a;
    const ushort* bu = (const ushort*)&b;
    float4 o0, o1;
    o0.x = w0 * bf2f(au[0]) + w1 * bf2f(bu[0]);
    o0.y = w0 * bf2f(au[1]) + w1 * bf2f(bu[1]);
    o0.z = w0 * bf2f(au[2]) + w1 * bf2f(bu[2]);
    o0.w = w0 * bf2f(au[3]) + w1 * bf2f(bu[3]);
    o1.x = w0 * bf2f(au[4]) + w1 * bf2f(bu[4]);
    o1.y = w0 * bf2f(au[5]) + w1 * bf2f(bu[5]);
    o1.z = w0 * bf2f(au[6]) + w1 * bf2f(bu[6]);
    o1.w = w0 * bf2f(au[7]) + w1 * bf2f(bu[7]);
    float4* dst = (float4*)(out + (size_t)t * CDIM + c8);
    dst[0] = o0; dst[1] = o1;
}

extern "C" void kernel_launch(void* const* d_in, const int* in_sizes, int n_in,
                              void* d_out, int out_size, void* d_ws, size_t ws_size,
                              hipStream_t stream) {
    const float* x      = (const float*)d_in[0];
    const float* Wr     = (const float*)d_in[1];
    const float* br     = (const float*)d_in[2];
    const float* Win    = (const float*)d_in[3];
    const float* conv_w = (const float*)d_in[4];
    const float* conv_b = (const float*)d_in[5];
    const float* Dp     = (const float*)d_in[6];
    const float* Wout   = (const float*)d_in[7];
    float* out = (float*)d_out;

    char* ws = (char*)d_ws;
    int*    counts     = (int*)(ws + 0);
    int*    cursor     = (int*)(ws + 128);
    int*    tok_e      = (int*)(ws + 4096);
    float*  tok_w      = (float*)(ws + 4096 + 1 * 65536);
    int*    perm_token = (int*)(ws + 4096 + 2 * 65536);
    int*    tok_slot   = (int*)(ws + 4096 + 3 * 65536);
    const size_t MB = 1u << 20;
    ushort* y     = (ushort*)(ws + MB);                               // 64 MB
    ushort* xb    = (ushort*)(ws + MB + 67108864);                    // 16 MB
    ushort* winb  = (ushort*)(ws + MB + 67108864 + 16777216);         // 64 MB
    ushort* woutb = (ushort*)(ws + MB + 67108864 + 16777216 + 67108864); // 32 MB
    ushort* so    = winb;  // slot_out aliases winb (dead after gemm1; 33.5 MB <= 64 MB)

    hipMemsetAsync(ws, 0, 256, stream);

    k_cvtWin<<<2048, 256, 0, stream>>>(Win, winb);
    k_router<<<NTOK / 4, 256, 0, stream>>>(x, Wr, br, counts, tok_e, tok_w, xb);
    k_scatter<<<NTOK / 256, 256, 0, stream>>>(tok_e, counts, cursor, perm_token,
                                              tok_slot, out + (size_t)NTOK * CDIM);

    k_gemm1<<<NEXP * 160, 512, 0, stream>>>(xb, winb, conv_w, conv_b, Dp,
                                            counts, perm_token, y, Wout, woutb);
    k_gemm2<<<512, 512, 0, stream>>>(y, woutb, counts, so);
    k_combine<<<NTOK * 128 / 256, 256, 0, stream>>>(so, tok_slot, tok_w, out);
}

// Round 20
// 595.412 us; speedup vs baseline: 1.5082x; 1.0422x over previous
//
#include <hip/hip_runtime.h>
#include <hip/hip_bf16.h>
#include <stdint.h>

#define NTOK 8192
#define CDIM 1024
#define DIN  2048
#define NEXP 8
#define NSLOT (NTOK * 2)

typedef __bf16 bf16x8 __attribute__((ext_vector_type(8)));
typedef float  f32x4  __attribute__((ext_vector_type(4)));

typedef __attribute__((address_space(1))) const unsigned char GBUF;
typedef __attribute__((address_space(3))) unsigned char LBUF;

__device__ __forceinline__ void gload_lds16(const void* g, void* l) {
    __builtin_amdgcn_global_load_lds((GBUF*)g, (LBUF*)l, 16, 0, 0);
}

__device__ __forceinline__ unsigned f2bf1(float f) {
    union { float f; unsigned u; } v; v.f = f;
    unsigned u = v.u;
    u += 0x7fffu + ((u >> 16) & 1u);   // RNE
    return u >> 16;
}
__device__ __forceinline__ ushort f2bf(float f) { return (ushort)f2bf1(f); }
__device__ __forceinline__ float bf2f(ushort u) {
    union { float f; unsigned u; } v; v.u = ((unsigned)u) << 16; return v.f;
}
__device__ __forceinline__ float silu_f(float x) { return x / (1.f + __expf(-x)); }

// pack two float4 into 8 bf16 (16 B)
__device__ __forceinline__ uint4 pack8(float4 a, float4 b) {
    uint4 o;
    o.x = f2bf1(a.x) | (f2bf1(a.y) << 16);
    o.y = f2bf1(a.z) | (f2bf1(a.w) << 16);
    o.z = f2bf1(b.x) | (f2bf1(b.y) << 16);
    o.w = f2bf1(b.z) | (f2bf1(b.w) << 16);
    return o;
}

// swizzled LDS fragment read: row-major [R][64] ushort tile, 16B chunk XOR'd by row&7
__device__ __forceinline__ bf16x8 lds_swz(const ushort* L, int row, int kof) {
    return *(const bf16x8*)&L[row * 64 + ((((kof >> 3) ^ row) & 7) << 3)];
}

// counted vmcnt wait: memory clobber pins vmem/ds ordering, MFMA/VALU stay free
#define WAITV(N) asm volatile("s_waitcnt vmcnt(" #N ")" ::: "memory")
#define BARR     __builtin_amdgcn_s_barrier()

// ---------------- router: one wave per token; emits x bf16; tail-converts Win ----------------
__global__ void __launch_bounds__(256) k_router(
    const float* __restrict__ x, const float* __restrict__ Wr,
    const float* __restrict__ br, int* __restrict__ counts,
    int* __restrict__ tok_e, float* __restrict__ tok_w,
    ushort* __restrict__ xb,
    const float* __restrict__ Win, ushort* __restrict__ winb) {
    int wave = blockIdx.x * 4 + (threadIdx.x >> 6);
    int lane = threadIdx.x & 63;
    const float4* row = (const float4*)(x + (size_t)wave * CDIM);
    ushort4* xrow = (ushort4*)(xb + (size_t)wave * CDIM);
    float acc[NEXP];
#pragma unroll
    for (int e = 0; e < NEXP; ++e) acc[e] = 0.f;
#pragma unroll
    for (int j = 0; j < 4; ++j) {
        float4 v = row[j * 64 + lane];
        ushort4 o;
        o.x = f2bf(v.x); o.y = f2bf(v.y); o.z = f2bf(v.z); o.w = f2bf(v.w);
        xrow[j * 64 + lane] = o;
#pragma unroll
        for (int e = 0; e < NEXP; ++e) {
            float4 w = ((const float4*)(Wr + e * CDIM))[j * 64 + lane];
            acc[e] += v.x * w.x + v.y * w.y + v.z * w.z + v.w * w.w;
        }
    }
#pragma unroll
    for (int off = 32; off > 0; off >>= 1)
#pragma unroll
        for (int e = 0; e < NEXP; ++e) acc[e] += __shfl_xor(acc[e], off, 64);
    if (lane == 0) {
        float l[NEXP];
#pragma unroll
        for (int e = 0; e < NEXP; ++e) l[e] = acc[e] + br[e];
        int i0 = 0; float l0 = l[0];
#pragma unroll
        for (int e = 1; e < NEXP; ++e) if (l[e] > l0) { l0 = l[e]; i0 = e; }
        int i1 = -1; float l1 = -1e30f;
#pragma unroll
        for (int e = 0; e < NEXP; ++e) if (e != i0 && l[e] > l1) { l1 = l[e]; i1 = e; }
        float s  = __expf(l1 - l0);   // renormalized top-2 softmax
        float w0 = 1.f / (1.f + s);
        float w1 = 1.f - w0;
        tok_e[wave * 2] = i0; tok_e[wave * 2 + 1] = i1;
        tok_w[wave * 2] = w0; tok_w[wave * 2 + 1] = w1;
        atomicAdd(&counts[i0], 1); atomicAdd(&counts[i1], 1);
    }
    // ---- tail-fill: convert this block's share of Win (fp32 -> bf16) ----
    // 4,194,304 uint4 outputs over 2048 blocks x 256 threads = 8 per thread
    {
        const float4* s = (const float4*)Win;
        uint4* d = (uint4*)winb;
        const int NOUT = NEXP * 2 * DIN * CDIM / 8;   // 4194304
        const int STRD = 2048 * 256;                  // 524288
#pragma unroll 1
        for (int i = blockIdx.x * 256 + threadIdx.x; i < NOUT; i += STRD) {
            float4 a = s[2 * i], bq = s[2 * i + 1];
            d[i] = pack8(a, bq);
        }
    }
}

// ---------------- scatter tokens into expert-grouped slots (+ aux loss) ----------------
__global__ void __launch_bounds__(256) k_scatter(
    const int* __restrict__ tok_e, const int* __restrict__ counts,
    int* __restrict__ cursor, int* __restrict__ perm_token,
    int* __restrict__ tok_slot, float* __restrict__ out_aux) {
    int t = blockIdx.x * 256 + threadIdx.x;
    if (t >= NTOK) return;
    if (t == 0) {
        float aux = 0.f;
#pragma unroll
        for (int k = 0; k < NEXP; ++k) {
            float ld = (float)counts[k] * (1.f / (float)NTOK);
            aux += ld * ld;
        }
        *out_aux = aux;
    }
#pragma unroll
    for (int k = 0; k < 2; ++k) {
        int e = tok_e[t * 2 + k];
        int off = 0, o = 0;
#pragma unroll
        for (int j = 0; j < NEXP; ++j) {
            if (j == e) off = o;
            o += counts[j];
        }
        int pos = atomicAdd(&cursor[e], 1);
        int s = off + pos;
        perm_token[s] = t;
        tok_slot[t * 2 + k] = s;
    }
}

// ---------------- grouped GEMM1: 256 slots x 128 y-cols (dual), BK=64 ----------------
// 4-phase/K-tile counted-vmcnt pipeline; post-loop tail converts Wout (fp32 -> bf16)
__global__ void __launch_bounds__(512, 2) k_gemm1(
    const ushort* __restrict__ xb, const ushort* __restrict__ Winb,
    const float* __restrict__ conv_w, const float* __restrict__ conv_b,
    const float* __restrict__ Dp, const int* __restrict__ counts,
    const int* __restrict__ perm_token, ushort* __restrict__ y,
    const float* __restrict__ Wout, ushort* __restrict__ woutb) {
    int h = blockIdx.x;                  // 1280 = 8 * 160
    int vb = (h & 7) * 160 + (h >> 3);   // expert-per-XCD swizzle, bijective
    int e   = vb / 160;
    int r   = vb % 160;
    int mt0 = r >> 4;                    // 0..9
    int nt  = r & 15;                    // 0..15 over DIN/128
    int base = 0;
#pragma unroll
    for (int k = 0; k < NEXP; ++k) if (k < e) base += counts[k];
    int cnt = counts[e];
    int mtiles = (cnt + 255) >> 8;
    int n0 = nt * 128;

    __shared__ ushort aL[2][256 * 64];   // 2 x 32 KB
    __shared__ ushort bL[2][256 * 64];   // 2 x 32 KB (128 xi rows + 128 z rows)

    int tid = threadIdx.x, lane = tid & 63, w = tid >> 6;
    int Mw = w >> 1, Nw = w & 1;         // wave tile: 64 slots x 64 y-cols (dual)
    const ushort* WinE = Winb + (size_t)e * (2 * DIN) * CDIM;
    int schunk = ((tid & 7) ^ ((tid >> 3) & 7)) << 3;   // pre-swizzled source chunk

    uint bsrc[4];
#pragma unroll
    for (int i = 0; i < 4; ++i) {
        int rr = i * 64 + (tid >> 3);    // 0..255
        int grow = (rr < 128) ? (n0 + rr) : (DIN + n0 + (rr - 128));
        bsrc[i] = (uint)grow * CDIM + schunk;
    }

    for (int mt = mt0; mt < mtiles; mt += 10) {
        int rem = cnt - mt * 256;
        uint asrc[4];
#pragma unroll
        for (int i = 0; i < 4; ++i) {
            int rr = i * 64 + (tid >> 3);
            int sidx = base + mt * 256 + (rr < rem ? rr : 0);
            asrc[i] = (uint)perm_token[sidx] * CDIM + schunk;
        }

        f32x4 accXi[4][4], accZ[4][4];
#pragma unroll
        for (int m = 0; m < 4; ++m)
#pragma unroll
            for (int n = 0; n < 4; ++n) {
                accXi[m][n] = f32x4{0.f, 0.f, 0.f, 0.f};
                accZ[m][n]  = f32x4{0.f, 0.f, 0.f, 0.f};
            }

        // staging: half-tile = 2 gloads (rows i*64 pair)
        auto stgA = [&](int bi, int ko, int i, int j) {
            gload_lds16(xb + asrc[i] + ko, &aL[bi][(i * 512 + tid) * 8]);
            gload_lds16(xb + asrc[j] + ko, &aL[bi][(j * 512 + tid) * 8]);
        };
        auto stgB = [&](int bi, int ko, int i, int j) {
            gload_lds16(WinE + bsrc[i] + ko, &bL[bi][(i * 512 + tid) * 8]);
            gload_lds16(WinE + bsrc[j] + ko, &bL[bi][(j * 512 + tid) * 8]);
        };

        bf16x8 af0[4], af1[4], bx[4], bz[4];
        // prologue: stage K-tile 0 into buf 0 (stage order: A0,A1,Bxi,Bz)
        stgA(0, 0, 0, 1); stgA(0, 0, 2, 3); stgB(0, 0, 0, 1); stgB(0, 0, 2, 3);

#pragma unroll 1
        for (int kt = 0; kt < 16; ++kt) {
            int cur = kt & 1, nxt = cur ^ 1;
            const ushort* A = aL[cur];
            const ushort* B = bL[cur];
            int ko = (kt + 1) * 64;
            bool st = kt < 15;
            // ---- ph0: xi kk0 (needs A0,A1,Bxi = oldest 6 of 8) ----
            WAITV(2);
            BARR;
#pragma unroll
            for (int m = 0; m < 4; ++m)
                af0[m] = lds_swz(A, Mw * 64 + m * 16 + (lane & 15), (lane >> 4) * 8);
#pragma unroll
            for (int n = 0; n < 4; ++n)
                bx[n] = lds_swz(B, Nw * 64 + n * 16 + (lane & 15), (lane >> 4) * 8);
            if (st) stgA(nxt, ko, 0, 1);
            __builtin_amdgcn_s_setprio(1);
#pragma unroll
            for (int m = 0; m < 4; ++m)
#pragma unroll
                for (int n = 0; n < 4; ++n)
                    accXi[m][n] = __builtin_amdgcn_mfma_f32_16x16x32_bf16(af0[m], bx[n], accXi[m][n], 0, 0, 0);
            __builtin_amdgcn_s_setprio(0);
            // ---- ph1: z kk0 (needs Bz = oldest 2 of remaining) ----
            if (st) { WAITV(2); } else { WAITV(0); }
            BARR;
#pragma unroll
            for (int n = 0; n < 4; ++n)
                bz[n] = lds_swz(B, 128 + Nw * 64 + n * 16 + (lane & 15), (lane >> 4) * 8);
            if (st) stgA(nxt, ko, 2, 3);
            __builtin_amdgcn_s_setprio(1);
#pragma unroll
            for (int m = 0; m < 4; ++m)
#pragma unroll
                for (int n = 0; n < 4; ++n)
                    accZ[m][n] = __builtin_amdgcn_mfma_f32_16x16x32_bf16(af0[m], bz[n], accZ[m][n], 0, 0, 0);
            __builtin_amdgcn_s_setprio(0);
            // ---- ph2: xi kk1 (all data already resident) ----
            BARR;
#pragma unroll
            for (int m = 0; m < 4; ++m)
                af1[m] = lds_swz(A, Mw * 64 + m * 16 + (lane & 15), 32 + (lane >> 4) * 8);
#pragma unroll
            for (int n = 0; n < 4; ++n)
                bx[n] = lds_swz(B, Nw * 64 + n * 16 + (lane & 15), 32 + (lane >> 4) * 8);
            if (st) stgB(nxt, ko, 0, 1);
            __builtin_amdgcn_s_setprio(1);
#pragma unroll
            for (int m = 0; m < 4; ++m)
#pragma unroll
                for (int n = 0; n < 4; ++n)
                    accXi[m][n] = __builtin_amdgcn_mfma_f32_16x16x32_bf16(af1[m], bx[n], accXi[m][n], 0, 0, 0);
            __builtin_amdgcn_s_setprio(0);
            // ---- ph3: z kk1 ----
            BARR;
#pragma unroll
            for (int n = 0; n < 4; ++n)
                bz[n] = lds_swz(B, 128 + Nw * 64 + n * 16 + (lane & 15), 32 + (lane >> 4) * 8);
            if (st) stgB(nxt, ko, 2, 3);
            __builtin_amdgcn_s_setprio(1);
#pragma unroll
            for (int m = 0; m < 4; ++m)
#pragma unroll
                for (int n = 0; n < 4; ++n)
                    accZ[m][n] = __builtin_amdgcn_mfma_f32_16x16x32_bf16(af1[m], bz[n], accZ[m][n], 0, 0, 0);
            __builtin_amdgcn_s_setprio(0);
        }
        __syncthreads();

        // epilogue: gated activation -> y (bf16)
#pragma unroll
        for (int n = 0; n < 4; ++n) {
            int c = n0 + Nw * 64 + n * 16 + (lane & 15);
            float cwl = conv_w[((size_t)e * DIN + c) * 4 + 3];
            float cb  = conv_b[(size_t)e * DIN + c];
            float dp  = Dp[(size_t)e * DIN + c];
#pragma unroll
            for (int m = 0; m < 4; ++m)
#pragma unroll
                for (int q = 0; q < 4; ++q) {
                    int rl = Mw * 64 + m * 16 + (lane >> 4) * 4 + q;
                    if (rl < rem) {
                        int slot = base + mt * 256 + rl;
                        float xi = accXi[m][n][q], z = accZ[m][n][q];
                        float yv = silu_f(xi * cwl + cb) * dp * silu_f(z);
                        y[(size_t)slot * DIN + c] = f2bf(yv);
                    }
                }
        }
        __syncthreads();
    }

    // ---- tail-fill: convert this block's share of Wout (fp32 -> bf16) ----
    {
        const float4* s = (const float4*)Wout;
        uint4* d = (uint4*)woutb;
        const int NOUT = NEXP * CDIM * DIN / 8;   // 2097152
        const int STRD = 1280 * 512;              // 655360
#pragma unroll 1
        for (int i = blockIdx.x * 512 + tid; i < NOUT; i += STRD) {
            float4 a = s[2 * i], bq = s[2 * i + 1];
            d[i] = pack8(a, bq);
        }
    }
}

// ---------------- grouped GEMM2: 256 slots x 128 out-cols, BK=64 ----------------
// single-buffer 48 KB LDS, 2 blocks/CU, flat balanced tile list (local prefix),
// writes per-slot bf16 results (no atomics; combined later)
__global__ void __launch_bounds__(512, 4) k_gemm2(
    const ushort* __restrict__ y, const ushort* __restrict__ Woutb,
    const int* __restrict__ counts, ushort* __restrict__ so) {
    __shared__ ushort aL[256 * 64];   // 32 KB (y slots)
    __shared__ ushort bL[128 * 64];   // 16 KB (Wout rows = out cols)

    int tid = threadIdx.x, lane = tid & 63, w = tid >> 6;
    int Mw = w >> 1, Nw = w & 1;      // wave tile: 64 slots x 64 cols
    int schunk = ((tid & 7) ^ ((tid >> 3) & 7)) << 3;

    int cn[NEXP];
#pragma unroll
    for (int k = 0; k < NEXP; ++k) cn[k] = counts[k];
    int tot_mtiles = 0;
#pragma unroll
    for (int k = 0; k < NEXP; ++k) tot_mtiles += (cn[k] + 255) >> 8;
    int ntiles = tot_mtiles * 8;      // x 8 n-tiles
    int b = blockIdx.x;
    int virt = (b & 7) * 64 + (b >> 3);   // XCD-chunk swizzle, 512 = 8*64

    for (int t = virt; t < ntiles; t += 512) {
        int pair = t >> 3, nt = t & 7;
        int e = 0, mt = pair, base = 0, cnt = cn[0];
        {
            int o = 0, tp = 0;
#pragma unroll
            for (int k = 0; k < NEXP; ++k) {
                int ck = cn[k];
                int tk = (ck + 255) >> 8;
                if (pair >= tp) { e = k; mt = pair - tp; base = o; cnt = ck; }
                o += ck; tp += tk;
            }
        }
        int rem = cnt - mt * 256;
        int c0 = nt * 128;
        const ushort* WoutE = Woutb + (size_t)e * CDIM * DIN;

        uint asrc[4], bsrc[2];
#pragma unroll
        for (int i = 0; i < 4; ++i) {
            int rr = i * 64 + (tid >> 3);
            int slot = base + mt * 256 + (rr < rem ? rr : 0);
            asrc[i] = (uint)slot * DIN + schunk;
        }
#pragma unroll
        for (int i = 0; i < 2; ++i) {
            int rr = i * 64 + (tid >> 3);
            bsrc[i] = (uint)(c0 + rr) * DIN + schunk;
        }

        f32x4 acc[4][4];
#pragma unroll
        for (int m = 0; m < 4; ++m)
#pragma unroll
            for (int n = 0; n < 4; ++n) acc[m][n] = f32x4{0.f, 0.f, 0.f, 0.f};

#pragma unroll 1
        for (int kt = 0; kt < 32; ++kt) {
            int ko = kt * 64;
            gload_lds16(y + asrc[0] + ko, &aL[(0 * 512 + tid) * 8]);
            gload_lds16(y + asrc[1] + ko, &aL[(1 * 512 + tid) * 8]);
            gload_lds16(y + asrc[2] + ko, &aL[(2 * 512 + tid) * 8]);
            gload_lds16(y + asrc[3] + ko, &aL[(3 * 512 + tid) * 8]);
            gload_lds16(WoutE + bsrc[0] + ko, &bL[(0 * 512 + tid) * 8]);
            gload_lds16(WoutE + bsrc[1] + ko, &bL[(1 * 512 + tid) * 8]);
            __syncthreads();
#pragma unroll
            for (int kk = 0; kk < 64; kk += 32) {
                int kof = kk + (lane >> 4) * 8;
                bf16x8 af[4], bf[4];
#pragma unroll
                for (int m = 0; m < 4; ++m)
                    af[m] = lds_swz(aL, Mw * 64 + m * 16 + (lane & 15), kof);
#pragma unroll
                for (int n = 0; n < 4; ++n)
                    bf[n] = lds_swz(bL, Nw * 64 + n * 16 + (lane & 15), kof);
                __builtin_amdgcn_s_setprio(1);
#pragma unroll
                for (int m = 0; m < 4; ++m)
#pragma unroll
                    for (int n = 0; n < 4; ++n)
                        acc[m][n] = __builtin_amdgcn_mfma_f32_16x16x32_bf16(af[m], bf[n], acc[m][n], 0, 0, 0);
                __builtin_amdgcn_s_setprio(0);
            }
            __syncthreads();
        }

        // epilogue: per-slot bf16 store (combined later)
#pragma unroll
        for (int m = 0; m < 4; ++m)
#pragma unroll
            for (int q = 0; q < 4; ++q) {
                int rl = Mw * 64 + m * 16 + (lane >> 4) * 4 + q;
                if (rl < rem) {
                    int slot = base + mt * 256 + rl;
#pragma unroll
                    for (int n = 0; n < 4; ++n) {
                        int col = c0 + Nw * 64 + n * 16 + (lane & 15);
                        so[(size_t)slot * CDIM + col] = f2bf(acc[m][n][q]);
                    }
                }
            }
        __syncthreads();
    }
}

// ---------------- combine: out[t] = w0*so[s0] + w1*so[s1] ----------------
__global__ void __launch_bounds__(256) k_combine(
    const ushort* __restrict__ so, const int* __restrict__ tok_slot,
    const float* __restrict__ tok_w, float* __restrict__ out) {
    int i = blockIdx.x * 256 + threadIdx.x;   // NTOK*128 threads
    int t  = i >> 7;
    int c8 = (i & 127) << 3;
    int s0 = tok_slot[t * 2], s1 = tok_slot[t * 2 + 1];
    float w0 = tok_w[t * 2],  w1 = tok_w[t * 2 + 1];
    uint4 a = *(const uint4*)(so + (size_t)s0 * CDIM + c8);
    uint4 b = *(const uint4*)(so + (size_t)s1 * CDIM + c8);
    const ushort* au = (const ushort*)&a;
    const ushort* bu = (const ushort*)&b;
    float4 o0, o1;
    o0.x = w0 * bf2f(au[0]) + w1 * bf2f(bu[0]);
    o0.y = w0 * bf2f(au[1]) + w1 * bf2f(bu[1]);
    o0.z = w0 * bf2f(au[2]) + w1 * bf2f(bu[2]);
    o0.w = w0 * bf2f(au[3]) + w1 * bf2f(bu[3]);
    o1.x = w0 * bf2f(au[4]) + w1 * bf2f(bu[4]);
    o1.y = w0 * bf2f(au[5]) + w1 * bf2f(bu[5]);
    o1.z = w0 * bf2f(au[6]) + w1 * bf2f(bu[6]);
    o1.w = w0 * bf2f(au[7]) + w1 * bf2f(bu[7]);
    float4* dst = (float4*)(out + (size_t)t * CDIM + c8);
    dst[0] = o0; dst[1] = o1;
}

extern "C" void kernel_launch(void* const* d_in, const int* in_sizes, int n_in,
                              void* d_out, int out_size, void* d_ws, size_t ws_size,
                              hipStream_t stream) {
    const float* x      = (const float*)d_in[0];
    const float* Wr     = (const float*)d_in[1];
    const float* br     = (const float*)d_in[2];
    const float* Win    = (const float*)d_in[3];
    const float* conv_w = (const float*)d_in[4];
    const float* conv_b = (const float*)d_in[5];
    const float* Dp     = (const float*)d_in[6];
    const float* Wout   = (const float*)d_in[7];
    float* out = (float*)d_out;

    char* ws = (char*)d_ws;
    int*    counts     = (int*)(ws + 0);
    int*    cursor     = (int*)(ws + 128);
    int*    tok_e      = (int*)(ws + 4096);
    float*  tok_w      = (float*)(ws + 4096 + 1 * 65536);
    int*    perm_token = (int*)(ws + 4096 + 2 * 65536);
    int*    tok_slot   = (int*)(ws + 4096 + 3 * 65536);
    const size_t MB = 1u << 20;
    ushort* y     = (ushort*)(ws + MB);                               // 64 MB
    ushort* xb    = (ushort*)(ws + MB + 67108864);                    // 16 MB
    ushort* winb  = (ushort*)(ws + MB + 67108864 + 16777216);         // 64 MB
    ushort* woutb = (ushort*)(ws + MB + 67108864 + 16777216 + 67108864); // 32 MB
    ushort* so    = winb;  // slot_out aliases winb (dead after gemm1; 33.5 MB <= 64 MB)

    hipMemsetAsync(ws, 0, 256, stream);

    k_router<<<NTOK / 4, 256, 0, stream>>>(x, Wr, br, counts, tok_e, tok_w, xb,
                                           Win, winb);
    k_scatter<<<NTOK / 256, 256, 0, stream>>>(tok_e, counts, cursor, perm_token,
                                              tok_slot, out + (size_t)NTOK * CDIM);

    k_gemm1<<<NEXP * 160, 512, 0, stream>>>(xb, winb, conv_w, conv_b, Dp,
                                            counts, perm_token, y, Wout, woutb);
    k_gemm2<<<512, 512, 0, stream>>>(y, woutb, counts, so);
    k_combine<<<NTOK * 128 / 256, 256, 0, stream>>>(so, tok_slot, tok_w, out);
}